// Round 7
// baseline (207.457 us; speedup 1.0000x reference)
//
#include <hip/hip_runtime.h>

#define HIDDEN 64
#define HALFD  32
#define VOCAB  64
#define BATCH  256
#define SEQLEN 2048

#define RLF(v, sl) __int_as_float(__builtin_amdgcn_readlane(__float_as_int(v), (sl)))
#define RLI(v, sl) __builtin_amdgcn_readlane((v), (sl))
// DPP cross-lane (VALU, no DS queue):
//   QPF(v,j): quad_perm[j,j,j,j]  -> lane l gets v[(l&~3)+j]
//   RORF4(v): row_ror:4           -> lane l gets v[(l&15)+4 mod 16 within row]
#define QPF(v, j)  __int_as_float(__builtin_amdgcn_update_dpp(__float_as_int(v), __float_as_int(v), 0x55 * (j), 0xF, 0xF, false))
#define RORF4(v)   __int_as_float(__builtin_amdgcn_update_dpp(__float_as_int(v), __float_as_int(v), 0x124, 0xF, 0xF, false))
#define GIX(j,m) (((j)==0?0:(j)==1?7:(j)==2?13:(j)==3?18:(j)==4?22:(j)==5?25:27) + (m) - (j) - 1)
#define OM(m) (((m)*((m)+1))>>1)

// ---------------------------------------------------------------------------
// Kernel 1: per-token vocab tables (R20 layout, known-passing).
//   ws[0    ..2047]  ks_voc [64][32]   ws[2048..4095] ke_voc
//   ws[4096 ..6143]  vs_voc           ws[6144..8191] ve_voc
//   ws[8192 ..16383] Gs,Ge [2][64][64]
// ---------------------------------------------------------------------------
__global__ __launch_bounds__(256) void vocab_kernel(
    const float* __restrict__ embed, const float* __restrict__ W1, const float* __restrict__ b1,
    const float* __restrict__ W2, const float* __restrict__ b2,
    const float* __restrict__ ln_g, const float* __restrict__ ln_b,
    const float* __restrict__ Ws, const float* __restrict__ bs,
    const float* __restrict__ We, const float* __restrict__ be,
    float* __restrict__ ws)
{
    const int v = blockIdx.x;
    const int tid = threadIdx.x;

    __shared__ float e_s[64];
    __shared__ float W1_s[128][65];
    __shared__ float W2_s[64][129];
    __shared__ float Wse_s[64][65];
    __shared__ float a1_s[128];
    __shared__ float h_s[64];

    if (tid < 64) e_s[tid] = embed[v * 64 + tid];
    {
        const float4* src = (const float4*)W1;
        for (int i = tid; i < 2048; i += 256) {
            float4 x4 = src[i];
            const int e = i << 2, r = e >> 6, c = e & 63;
            W1_s[r][c] = x4.x; W1_s[r][c+1] = x4.y; W1_s[r][c+2] = x4.z; W1_s[r][c+3] = x4.w;
        }
    }
    __syncthreads();

    if (tid < 128) {
        float p0 = b1[tid], p1 = 0.f, p2 = 0.f, p3 = 0.f;
        #pragma unroll
        for (int m = 0; m < 64; m += 4) {
            p0 = fmaf(e_s[m],   W1_s[tid][m],   p0);
            p1 = fmaf(e_s[m+1], W1_s[tid][m+1], p1);
            p2 = fmaf(e_s[m+2], W1_s[tid][m+2], p2);
            p3 = fmaf(e_s[m+3], W1_s[tid][m+3], p3);
        }
        a1_s[tid] = fmaxf((p0 + p1) + (p2 + p3), 0.0f);
    } else {
        const float4* src = (const float4*)W2;
        for (int i = tid - 128; i < 2048; i += 128) {
            float4 x4 = src[i];
            const int e = i << 2, r = e >> 7, c = e & 127;
            W2_s[r][c] = x4.x; W2_s[r][c+1] = x4.y; W2_s[r][c+2] = x4.z; W2_s[r][c+3] = x4.w;
        }
    }
    __syncthreads();

    if (tid < 64) {
        float f0 = b2[tid], f1 = 0.f, f2 = 0.f, f3 = 0.f;
        #pragma unroll
        for (int m = 0; m < 128; m += 4) {
            f0 = fmaf(a1_s[m],   W2_s[tid][m],   f0);
            f1 = fmaf(a1_s[m+1], W2_s[tid][m+1], f1);
            f2 = fmaf(a1_s[m+2], W2_s[tid][m+2], f2);
            f3 = fmaf(a1_s[m+3], W2_s[tid][m+3], f3);
        }
        float x = e_s[tid] + ((f0 + f1) + (f2 + f3));
        float s = x, s2 = x * x;
        #pragma unroll
        for (int off = 32; off >= 1; off >>= 1) {
            s  += __shfl_xor(s,  off, 64);
            s2 += __shfl_xor(s2, off, 64);
        }
        float mu  = s * (1.0f / 64.0f);
        float var = s2 * (1.0f / 64.0f) - mu * mu;
        h_s[tid] = (x - mu) * rsqrtf(var + 1e-5f) * ln_g[tid] + ln_b[tid];
    } else if (tid < 192) {
        const int t2 = tid - 64;
        const float4* s1 = (const float4*)Ws;
        const float4* s2 = (const float4*)We;
        for (int i = t2; i < 512; i += 128) {
            float4 x4 = s1[i];
            const int e = i << 2, r = e >> 6, c = e & 63;
            Wse_s[r][c] = x4.x; Wse_s[r][c+1] = x4.y; Wse_s[r][c+2] = x4.z; Wse_s[r][c+3] = x4.w;
        }
        for (int i = t2; i < 512; i += 128) {
            float4 x4 = s2[i];
            const int e = i << 2, r = e >> 6, c = e & 63;
            Wse_s[32+r][c] = x4.x; Wse_s[32+r][c+1] = x4.y; Wse_s[32+r][c+2] = x4.z; Wse_s[32+r][c+3] = x4.w;
        }
    }
    __syncthreads();

    if (tid < 64) {
        const int j = tid & 31;
        const bool is_s = tid < 32;
        float c0 = is_s ? bs[j] : be[j];
        float c1 = 0.f, c2 = 0.f, c3 = 0.f;
        #pragma unroll
        for (int m = 0; m < 64; m += 4) {
            c0 = fmaf(h_s[m],   Wse_s[tid][m],   c0);
            c1 = fmaf(h_s[m+1], Wse_s[tid][m+1], c1);
            c2 = fmaf(h_s[m+2], Wse_s[tid][m+2], c2);
            c3 = fmaf(h_s[m+3], Wse_s[tid][m+3], c3);
        }
        float acc = (c0 + c1) + (c2 + c3);

        float n2 = acc * acc;
        #pragma unroll
        for (int off = 16; off >= 1; off >>= 1) n2 += __shfl_xor(n2, off, 64);
        float norm = sqrtf(n2);
        float kn = acc / fmaxf(norm, 1e-12f);

        const int base = v * 32 + j;
        if (is_s) { ws[base]        = kn; ws[4096 + base] = acc; }
        else      { ws[2048 + base] = kn; ws[6144 + base] = acc; }
    }
}

// ---------------------------------------------------------------------------
// Kernel 1b: Gram tables G_w[a][b] = k_w[a].k_w[b], [64][64] in ws.
// ---------------------------------------------------------------------------
__global__ __launch_bounds__(256) void gram_kernel(float* __restrict__ ws)
{
    const int w   = blockIdx.x & 1;
    const int seg = blockIdx.x >> 1;
    const int tid = threadIdx.x;
    __shared__ float k_s[64][33];
    const float* kb = ws + w * 2048;
    for (int i = tid; i < 2048; i += 256) k_s[i >> 5][i & 31] = kb[i];
    __syncthreads();
    const int a  = seg * 16 + (tid >> 4);
    const int b0 = (tid & 15) << 2;
    float* Gw = ws + 8192 + w * 4096 + a * 64;
    #pragma unroll
    for (int bb = 0; bb < 4; ++bb) {
        const int bcol = b0 + bb;
        float acc0 = 0.f, acc1 = 0.f;
        #pragma unroll
        for (int m = 0; m < 32; m += 2) {
            acc0 = fmaf(k_s[a][m],     k_s[bcol][m],     acc0);
            acc1 = fmaf(k_s[a][m + 1], k_s[bcol][m + 1], acc1);
        }
        Gw[bcol] = acc0 + acc1;
    }
}

// chunk-8 solve-matrix build (verbatim R9 math)
static __device__ __forceinline__ void build_wpack(
    const int* tj, float fb, float invL, bool is_e, bool is_last, float* Wp,
    const float* __restrict__ Gg)
{
    float f[8];
    #pragma unroll
    for (int j = 0; j < 8; ++j) f[j] = is_e ? (fb + (float)j * invL) : 1.0f;
    if (is_last) f[7] = 0.0f;     // position 2047 is the query, not a write

    float g[28];
    #pragma unroll
    for (int j = 0; j < 7; ++j)
        #pragma unroll
        for (int m = j + 1; m < 8; ++m) g[GIX(j, m)] = Gg[tj[j] * 64 + tj[m]];

    #pragma unroll
    for (int m = 0; m < 8; ++m) {
        float col[8];
        col[m] = f[m];
        #pragma unroll
        for (int j = 6; j >= 0; --j) {
            if (j < m) {
                float acc = 0.0f;
                #pragma unroll
                for (int p = 1; p < 8; ++p)
                    if (p > j && p <= m) acc = fmaf(g[GIX(j, p)], col[p], acc);
                col[j] = -f[j] * acc;
            }
        }
        #pragma unroll
        for (int j = 0; j < 8; ++j)
            if (j <= m) Wp[OM(m) + j] = col[j];
    }
}

struct Chunk {
    int   tokv;      // lane-vector: tok[c*8 + (lane&7)]
    int   tk[8];     // uniform tokens of this chunk (SGPR via v_readlane)
    float grow[8];   // G[tok_j][lane]
    float R[8];      // per-lane W row: lane l7=i holds R_i[m]=Wp[OM(m)+i] (m>=i)
    float braw;      // corrected-gather input: shfl(u_{c+1}, tok_c), 2-body slack
    float bp[8];     // correction Gram block: bpermute 1-body early
};

// DPP broadcast of an 8-periodic lane value: returns all 8 slot values.
// v[l] depends only on l&7. p = lane&4 parity. a_j = quad_perm_j(v) =
// slot (j + (l&4)); b_j = quad_perm_j(row_ror4(v)) = slot (j + 4 - (l&4)).
// Pure VALU: 1 ror + 8 quad_perm + 8 cndmask, no DS queue, no SGPR hazard.
#define DPP_BCAST8(v, o0,o1,o2,o3,o4,o5,o6,o7, hi4)                         \
    {                                                                        \
        float _r = RORF4(v);                                                 \
        float _a0 = QPF(v,0), _a1 = QPF(v,1), _a2 = QPF(v,2), _a3 = QPF(v,3);\
        float _b0 = QPF(_r,0), _b1 = QPF(_r,1), _b2 = QPF(_r,2), _b3 = QPF(_r,3);\
        o0 = hi4 ? _b0 : _a0;  o1 = hi4 ? _b1 : _a1;                         \
        o2 = hi4 ? _b2 : _a2;  o3 = hi4 ? _b3 : _a3;                         \
        o4 = hi4 ? _a0 : _b0;  o5 = hi4 ? _a1 : _b1;                         \
        o6 = hi4 ? _a2 : _b2;  o7 = hi4 ? _a3 : _b3;                         \
    }

// ---------------------------------------------------------------------------
// Kernel 2 (R23): R5 structure (102.4us) with the two on-spine ds_swizzle
// broadcast rounds replaced by DPP (VALU) broadcast networks.
// Evidence: per-spine-round cost ~400-550cyc is the invariant across
// R0/R1/R2/R3/R5/R6 (R5: 256 bodies x 2 rounds ~ 480/round; R6: 128 x 4
// ~ 545/round) -> the floor is the LDS-crossbar round-trip. DPP quad_perm +
// row_ror:4 + parity cndmask redistributes an 8-periodic value entirely in
// the VALU pipe (17 ops, ~zero stall). Spine is now pure VALU; all DS ops
// (bp bpermutes, W ds_reads, braw) remain >=1 body off-spine.
// ---------------------------------------------------------------------------
__global__ __launch_bounds__(128) void scan_kernel(
    const int* __restrict__ seq, const float* __restrict__ ws,
    const float* __restrict__ Wrp, const float* __restrict__ brp,
    const float* __restrict__ Wo, const float* __restrict__ bo,
    float* __restrict__ out)
{
    const int b    = blockIdx.x;
    const int tid  = threadIdx.x;        // 0..127
    const int w    = tid >> 6;           // wave: 0 = s-branch, 1 = e-branch
    const int lane = tid & 63;
    const int l7   = lane & 7;
    const bool hi4 = (lane & 4) != 0;
    const bool is_e = (w == 1);

    __shared__ __align__(16) float Wlds[2][256][8][8];   // 128 KB
    __shared__ __align__(16) int   toklds[SEQLEN];       // 8 KB (prologue only)
    __shared__ float wacc_s[2][64];
    __shared__ float r_s[64];
    __shared__ float t1_s[64];

    const float* Gg = ws + 8192 + w * 4096;
    const int*   sq = seq + b * SEQLEN;

    // ---- stage token sequence (for the W-build prologue) ----
    {
        const int4* sq4 = (const int4*)sq;
        int4* tl4 = (int4*)toklds;
        #pragma unroll
        for (int i = 0; i < 4; ++i) tl4[tid + i * 128] = sq4[tid + i * 128];
    }
    __syncthreads();

    // ---- precompute W row-tables: lanes parallel over chunks (4 per lane) ----
    {
        const float invL = 1.0f / (float)SEQLEN;
        #pragma unroll
        for (int qq = 0; qq < 4; ++qq) {
            const int c = lane + (qq << 6);
            int tj[8];
            #pragma unroll
            for (int j = 0; j < 8; ++j) tj[j] = toklds[c * 8 + j];
            float Wp[36];
            build_wpack(tj, (float)(8 * c + 1) * invL, invL, is_e, c == 255, Wp, Gg);
            const int cx = c & 7;
            #pragma unroll
            for (int i = 0; i < 8; ++i) {
                float r[8];
                #pragma unroll
                for (int m = 0; m < 8; ++m) r[m] = (m >= i) ? Wp[OM(m) + i] : 0.0f;
                float4* dst = (float4*)&Wlds[w][c][i ^ cx][0];
                dst[0] = make_float4(r[0], r[1], r[2], r[3]);
                dst[1] = make_float4(r[4], r[5], r[6], r[7]);
            }
        }
    }
    __syncthreads();

    // ---- serial backward sweep ----
    Chunk A, B;
    float u, wacc0 = 0.0f, wacc1 = 0.0f;
    float sp0, sp1, sp2, sp3, sp4, sp5, sp6, sp7;

    // prologue: chunk 255 fully; chunk 254 tokens + braw + bp; chunk 253 tokens
    A.tokv = sq[2040 + l7];
    B.tokv = sq[2032 + l7];
    int tv2 = sq[2024 + l7];
    #pragma unroll
    for (int j = 0; j < 8; ++j) A.tk[j] = RLI(A.tokv, j);
    #pragma unroll
    for (int j = 0; j < 8; ++j) A.grow[j] = Gg[A.tk[j] * 64 + lane];
    {
        const float4* rp = (const float4*)&Wlds[w][255][l7 ^ 7][0];
        float4 lo = rp[0], hi = rp[1];
        A.R[0] = lo.x; A.R[1] = lo.y; A.R[2] = lo.z; A.R[3] = lo.w;
        A.R[4] = hi.x; A.R[5] = hi.y; A.R[6] = hi.z; A.R[7] = hi.w;
    }
    u = Gg[A.tk[7] * 64 + lane];           // query token = position 2047
    A.braw = __shfl(u, A.tokv, 64);        // t_255 raw (corr = 0)
    B.braw = __shfl(u, B.tokv, 64);        // braw'_254 = shfl(u_255, tok_254)
    #pragma unroll
    for (int j = 0; j < 8; ++j) {
        A.bp[j] = 0.0f;
        B.bp[j] = __shfl(A.grow[j], B.tokv, 64);   // G[tk255_j][tk254_l7]
    }
    sp0 = sp1 = sp2 = sp3 = sp4 = sp5 = sp6 = sp7 = 0.0f;

    auto body = [&](Chunk& cur, Chunk& nxt, int c) {
        const int cm1 = (c > 0) ? c - 1 : 0;
        const int cm3 = (c > 2) ? c - 3 : 0;

        // ---- spine head: corrected gather  t = braw' - bp . s_prev ----
        float c01 = fmaf(cur.bp[1], sp1, cur.bp[0] * sp0);
        float c23 = fmaf(cur.bp[3], sp3, cur.bp[2] * sp2);
        float c45 = fmaf(cur.bp[5], sp5, cur.bp[4] * sp4);
        float c67 = fmaf(cur.bp[7], sp7, cur.bp[6] * sp6);
        float tl = cur.braw - ((c01 + c23) + (c45 + c67));

        // ---- t broadcast: DPP network (pure VALU) ----
        float t0, t1, t2, t3, t4, t5, t6, t7;
        DPP_BCAST8(tl, t0, t1, t2, t3, t4, t5, t6, t7, hi4);

        // ---- prefetch chunk c-1 into nxt (off-spine filler) ----
        #pragma unroll
        for (int j = 0; j < 8; ++j) nxt.bp[j] = __shfl(cur.grow[j], nxt.tokv, 64);
        #pragma unroll
        for (int j = 0; j < 8; ++j) nxt.tk[j] = RLI(nxt.tokv, j);
        #pragma unroll
        for (int j = 0; j < 8; ++j) nxt.grow[j] = Gg[nxt.tk[j] * 64 + lane];
        {
            const float4* rp = (const float4*)&Wlds[w][cm1][l7 ^ (cm1 & 7)][0];
            float4 lo = rp[0], hi = rp[1];
            nxt.R[0] = lo.x; nxt.R[1] = lo.y; nxt.R[2] = lo.z; nxt.R[3] = lo.w;
            nxt.R[4] = hi.x; nxt.R[5] = hi.y; nxt.R[6] = hi.z; nxt.R[7] = hi.w;
        }
        int tv3 = sq[cm3 * 8 + l7];          // tokens of chunk c-3 (per-lane VMEM)

        // ---- spine: distributed s (lane l7=i computes s_i) ----
        const float* R = cur.R;
        float a0 = fmaf(R[1], t1, R[0] * t0);
        float a1 = fmaf(R[3], t3, R[2] * t2);
        float a2 = fmaf(R[5], t5, R[4] * t4);
        float a3 = fmaf(R[7], t7, R[6] * t6);
        float sd = (a0 + a1) + (a2 + a3);

        // ---- s broadcast: DPP network (pure VALU) ----
        float s0, s1, s2, s3, s4, s5, s6, s7;
        DPP_BCAST8(sd, s0, s1, s2, s3, s4, s5, s6, s7, hi4);

        // ---- u update, then braw for chunk c-2 (2-body slack) ----
        float dA = fmaf(cur.grow[0], s0, fmaf(cur.grow[1], s1, fmaf(cur.grow[2], s2, cur.grow[3] * s3)));
        float dB = fmaf(cur.grow[4], s4, fmaf(cur.grow[5], s5, fmaf(cur.grow[6], s6, cur.grow[7] * s7)));
        u -= (dA + dB);
        cur.braw = __shfl(u, tv2, 64);       // braw'_{c-2} = shfl(u_{c-1}, tok_{c-2})

        // ---- wacc[tok_j] += s_j  (lane = token; off-spine, 2 partials) ----
        wacc0 += (lane == cur.tk[0]) ? s0 : 0.0f;
        wacc1 += (lane == cur.tk[1]) ? s1 : 0.0f;
        wacc0 += (lane == cur.tk[2]) ? s2 : 0.0f;
        wacc1 += (lane == cur.tk[3]) ? s3 : 0.0f;
        wacc0 += (lane == cur.tk[4]) ? s4 : 0.0f;
        wacc1 += (lane == cur.tk[5]) ? s5 : 0.0f;
        wacc0 += (lane == cur.tk[6]) ? s6 : 0.0f;
        wacc1 += (lane == cur.tk[7]) ? s7 : 0.0f;

        // ---- rotate pipeline registers ----
        cur.tokv = tv2; tv2 = tv3;
        sp0 = s0; sp1 = s1; sp2 = s2; sp3 = s3;
        sp4 = s4; sp5 = s5; sp6 = s6; sp7 = s7;
    };

    for (int c = 255; c >= 1; c -= 2) {
        body(A, B, c);
        body(B, A, c - 1);
    }

    wacc_s[w][lane] = wacc0 + wacc1;
    __syncthreads();

    // r[w2][rho] = sum_tok wacc[w2][tok] * v[w2][tok][rho]  (v from global ws)
    if (tid < 64) {
        const int w2  = tid >> 5;
        const int rho = tid & 31;
        const float* vv = ws + 4096 + w2 * 2048;
        const float* wa = &wacc_s[w2][0];
        float acc = 0.0f;
        #pragma unroll 8
        for (int tok = 0; tok < 64; ++tok) acc = fmaf(wa[tok], vv[tok * 32 + rho], acc);
        r_s[tid] = acc;
    }
    __syncthreads();

    // out = (r @ Wrp.T + brp) @ Wo.T + bo
    if (tid < 64) {
        float acc = brp[tid];
        #pragma unroll 8
        for (int m = 0; m < 64; ++m) acc = fmaf(Wrp[tid * 64 + m], r_s[m], acc);
        t1_s[tid] = acc;
    }
    __syncthreads();
    if (tid < 64) {
        float acc = bo[tid];
        #pragma unroll 8
        for (int m = 0; m < 64; ++m) acc = fmaf(Wo[tid * 64 + m], t1_s[m], acc);
        out[b * 64 + tid] = acc;
    }
}

extern "C" void kernel_launch(void* const* d_in, const int* in_sizes, int n_in,
                              void* d_out, int out_size, void* d_ws, size_t ws_size,
                              hipStream_t stream)
{
    const int*   seq   = (const int*)  d_in[0];
    const float* embed = (const float*)d_in[1];
    const float* W1    = (const float*)d_in[2];
    const float* b1    = (const float*)d_in[3];
    const float* W2    = (const float*)d_in[4];
    const float* b2    = (const float*)d_in[5];
    const float* ln_g  = (const float*)d_in[6];
    const float* ln_b  = (const float*)d_in[7];
    const float* Ws    = (const float*)d_in[8];
    const float* bs    = (const float*)d_in[9];
    const float* We    = (const float*)d_in[10];
    const float* be    = (const float*)d_in[11];
    const float* Wrp   = (const float*)d_in[12];
    const float* brp   = (const float*)d_in[13];
    const float* Wo    = (const float*)d_in[14];
    const float* bo    = (const float*)d_in[15];
    float* ws  = (float*)d_ws;
    float* out = (float*)d_out;

    hipLaunchKernelGGL(vocab_kernel, dim3(VOCAB), dim3(256), 0, stream,
                       embed, W1, b1, W2, b2, ln_g, ln_b, Ws, bs, We, be, ws);
    hipLaunchKernelGGL(gram_kernel, dim3(8), dim3(256), 0, stream, ws);
    hipLaunchKernelGGL(scan_kernel, dim3(BATCH), dim3(128), 0, stream,
                       seq, ws, Wrp, brp, Wo, bo, out);
}

// Round 8
// 191.987 us; speedup vs baseline: 1.0806x; 1.0806x over previous
//
#include <hip/hip_runtime.h>

#define HIDDEN 64
#define HALFD  32
#define VOCAB  64
#define BATCH  256
#define SEQLEN 2048

#define RLI(v, sl) __builtin_amdgcn_readlane((v), (sl))
// lane-j broadcast within each 32-lane half (valid: value is 16-periodic)
#define SWZF(v, j) __int_as_float(__builtin_amdgcn_ds_swizzle(__float_as_int(v), ((j) << 5)))
#define OM(m) (((m)*((m)+1))>>1)

// ---------------------------------------------------------------------------
// Kernel 1: per-token vocab tables (R20 layout, known-passing).
//   ws[0..2047] ks | ws[2048..4095] ke | ws[4096..6143] vs | ws[6144..8191] ve
//   ws[8192..16383] Gs,Ge [2][64][64]
// ---------------------------------------------------------------------------
__global__ __launch_bounds__(256) void vocab_kernel(
    const float* __restrict__ embed, const float* __restrict__ W1, const float* __restrict__ b1,
    const float* __restrict__ W2, const float* __restrict__ b2,
    const float* __restrict__ ln_g, const float* __restrict__ ln_b,
    const float* __restrict__ Ws, const float* __restrict__ bs,
    const float* __restrict__ We, const float* __restrict__ be,
    float* __restrict__ ws)
{
    const int v = blockIdx.x;
    const int tid = threadIdx.x;

    __shared__ float e_s[64];
    __shared__ float W1_s[128][65];
    __shared__ float W2_s[64][129];
    __shared__ float Wse_s[64][65];
    __shared__ float a1_s[128];
    __shared__ float h_s[64];

    if (tid < 64) e_s[tid] = embed[v * 64 + tid];
    {
        const float4* src = (const float4*)W1;
        for (int i = tid; i < 2048; i += 256) {
            float4 x4 = src[i];
            const int e = i << 2, r = e >> 6, c = e & 63;
            W1_s[r][c] = x4.x; W1_s[r][c+1] = x4.y; W1_s[r][c+2] = x4.z; W1_s[r][c+3] = x4.w;
        }
    }
    __syncthreads();

    if (tid < 128) {
        float p0 = b1[tid], p1 = 0.f, p2 = 0.f, p3 = 0.f;
        #pragma unroll
        for (int m = 0; m < 64; m += 4) {
            p0 = fmaf(e_s[m],   W1_s[tid][m],   p0);
            p1 = fmaf(e_s[m+1], W1_s[tid][m+1], p1);
            p2 = fmaf(e_s[m+2], W1_s[tid][m+2], p2);
            p3 = fmaf(e_s[m+3], W1_s[tid][m+3], p3);
        }
        a1_s[tid] = fmaxf((p0 + p1) + (p2 + p3), 0.0f);
    } else {
        const float4* src = (const float4*)W2;
        for (int i = tid - 128; i < 2048; i += 128) {
            float4 x4 = src[i];
            const int e = i << 2, r = e >> 7, c = e & 127;
            W2_s[r][c] = x4.x; W2_s[r][c+1] = x4.y; W2_s[r][c+2] = x4.z; W2_s[r][c+3] = x4.w;
        }
    }
    __syncthreads();

    if (tid < 64) {
        float f0 = b2[tid], f1 = 0.f, f2 = 0.f, f3 = 0.f;
        #pragma unroll
        for (int m = 0; m < 128; m += 4) {
            f0 = fmaf(a1_s[m],   W2_s[tid][m],   f0);
            f1 = fmaf(a1_s[m+1], W2_s[tid][m+1], f1);
            f2 = fmaf(a1_s[m+2], W2_s[tid][m+2], f2);
            f3 = fmaf(a1_s[m+3], W2_s[tid][m+3], f3);
        }
        float x = e_s[tid] + ((f0 + f1) + (f2 + f3));
        float s = x, s2 = x * x;
        #pragma unroll
        for (int off = 32; off >= 1; off >>= 1) {
            s  += __shfl_xor(s,  off, 64);
            s2 += __shfl_xor(s2, off, 64);
        }
        float mu  = s * (1.0f / 64.0f);
        float var = s2 * (1.0f / 64.0f) - mu * mu;
        h_s[tid] = (x - mu) * rsqrtf(var + 1e-5f) * ln_g[tid] + ln_b[tid];
    } else if (tid < 192) {
        const int t2 = tid - 64;
        const float4* s1 = (const float4*)Ws;
        const float4* s2 = (const float4*)We;
        for (int i = t2; i < 512; i += 128) {
            float4 x4 = s1[i];
            const int e = i << 2, r = e >> 6, c = e & 63;
            Wse_s[r][c] = x4.x; Wse_s[r][c+1] = x4.y; Wse_s[r][c+2] = x4.z; Wse_s[r][c+3] = x4.w;
        }
        for (int i = t2; i < 512; i += 128) {
            float4 x4 = s2[i];
            const int e = i << 2, r = e >> 6, c = e & 63;
            Wse_s[32+r][c] = x4.x; Wse_s[32+r][c+1] = x4.y; Wse_s[32+r][c+2] = x4.z; Wse_s[32+r][c+3] = x4.w;
        }
    }
    __syncthreads();

    if (tid < 64) {
        const int j = tid & 31;
        const bool is_s = tid < 32;
        float c0 = is_s ? bs[j] : be[j];
        float c1 = 0.f, c2 = 0.f, c3 = 0.f;
        #pragma unroll
        for (int m = 0; m < 64; m += 4) {
            c0 = fmaf(h_s[m],   Wse_s[tid][m],   c0);
            c1 = fmaf(h_s[m+1], Wse_s[tid][m+1], c1);
            c2 = fmaf(h_s[m+2], Wse_s[tid][m+2], c2);
            c3 = fmaf(h_s[m+3], Wse_s[tid][m+3], c3);
        }
        float acc = (c0 + c1) + (c2 + c3);

        float n2 = acc * acc;
        #pragma unroll
        for (int off = 16; off >= 1; off >>= 1) n2 += __shfl_xor(n2, off, 64);
        float norm = sqrtf(n2);
        float kn = acc / fmaxf(norm, 1e-12f);

        const int base = v * 32 + j;
        if (is_s) { ws[base]        = kn; ws[4096 + base] = acc; }
        else      { ws[2048 + base] = kn; ws[6144 + base] = acc; }
    }
}

// ---------------------------------------------------------------------------
// Kernel 1b: Gram tables G_w[a][b] = k_w[a].k_w[b], [64][64] in ws.
// ---------------------------------------------------------------------------
__global__ __launch_bounds__(256) void gram_kernel(float* __restrict__ ws)
{
    const int w   = blockIdx.x & 1;
    const int seg = blockIdx.x >> 1;
    const int tid = threadIdx.x;
    __shared__ float k_s[64][33];
    const float* kb = ws + w * 2048;
    for (int i = tid; i < 2048; i += 256) k_s[i >> 5][i & 31] = kb[i];
    __syncthreads();
    const int a  = seg * 16 + (tid >> 4);
    const int b0 = (tid & 15) << 2;
    float* Gw = ws + 8192 + w * 4096 + a * 64;
    #pragma unroll
    for (int bb = 0; bb < 4; ++bb) {
        const int bcol = b0 + bb;
        float acc0 = 0.f, acc1 = 0.f;
        #pragma unroll
        for (int m = 0; m < 32; m += 2) {
            acc0 = fmaf(k_s[a][m],     k_s[bcol][m],     acc0);
            acc1 = fmaf(k_s[a][m + 1], k_s[bcol][m + 1], acc1);
        }
        Gw[bcol] = acc0 + acc1;
    }
}

// chunk-8 solve-matrix build (verbatim R9 math)
static __device__ __forceinline__ void build_wpack(
    const int* tj, float fb, float invL, bool is_e, bool is_last, float* Wp,
    const float* __restrict__ Gg)
{
    float f[8];
    #pragma unroll
    for (int j = 0; j < 8; ++j) f[j] = is_e ? (fb + (float)j * invL) : 1.0f;
    if (is_last) f[7] = 0.0f;     // position 2047 is the query, not a write

    float g[28];
    #pragma unroll
    for (int j = 0; j < 7; ++j)
        #pragma unroll
        for (int m = j + 1; m < 8; ++m)
            g[OM(m - 1) + j] = Gg[tj[j] * 64 + tj[m]];   // g[j<m] packed by (m-1) tri

    #pragma unroll
    for (int m = 0; m < 8; ++m) {
        float col[8];
        col[m] = f[m];
        #pragma unroll
        for (int j = 6; j >= 0; --j) {
            if (j < m) {
                float acc = 0.0f;
                #pragma unroll
                for (int p = 1; p < 8; ++p)
                    if (p > j && p <= m) acc = fmaf(g[OM(p - 1) + j], col[p], acc);
                col[j] = -f[j] * acc;
            }
        }
        #pragma unroll
        for (int j = 0; j < 8; ++j)
            if (j <= m) Wp[OM(m) + j] = col[j];
    }
}

// chunk-16 state. Slots 0..7 = EARLY chunk-8 (2C), 8..15 = LATE (2C+1).
struct C16 {
    int   tokv;      // lane-vector: tok[C*16 + (lane&15)]
    int   tk[16];    // uniform tokens (SGPR via v_readlane)
    float grow[16];  // G[tok_slot][lane]
    float row[16];   // distributed solve row (lane l15):
                     //   l15=i<8 : [W2 row i | -M2 row i]   (s2 = W2 tE - M2 tL)
                     //   l15=8+q : [0...0    | W1 row q ]   (s1 = W1 tL)
    float braw;      // shfl(u, tokv) issued 2 bodies early
    float bpp[16];   // G[tokprev_slot][tok_l15] (bpermute, 1 body early)
};

// ---------------------------------------------------------------------------
// Kernel 2 (R24): chunk-16 bodies at chunk-8 ROUND DEPTH via folded coupling.
// Law from R0-R7: time = #bodies x (~500cyc fixed) + issue; the fixed part is
// insensitive to body internals. R6's chunk-16 failed due to 4 dependent
// broadcast rounds. Fix: precompute M2 = W2 * Gx^T * W1 per chunk-16 in the
// prologue, so BOTH sub-solves happen in ONE distributed round:
//   round 1: t bcast (16 slots);  round 2: s bcast, where
//   lane i<8:  s2_i = sum_m W2[i][m] tE_m - sum_n M2[i][n] tL_n  (16 FMA)
//   lane 8+q:  s1_q = sum_n W1[q][n] tL_n                        (8 FMA)
// 128 bodies x 2 rounds (vs R5's 256 x 2). Math = R6 (passed) reassociated.
// LDS: packed-tri W rows + dense -M2 + zero-pad slot = 137 f/chunk -> 140KB.
// ---------------------------------------------------------------------------
__global__ __launch_bounds__(128) void scan_kernel(
    const int* __restrict__ seq, const float* __restrict__ ws,
    const float* __restrict__ Wrp, const float* __restrict__ brp,
    const float* __restrict__ Wo, const float* __restrict__ bo,
    float* __restrict__ out)
{
    const int b    = blockIdx.x;
    const int tid  = threadIdx.x;        // 0..127
    const int w    = tid >> 6;           // wave: 0 = s-branch, 1 = e-branch
    const int lane = tid & 63;
    const int l15  = lane & 15;
    const bool is_e = (w == 1);

    __shared__ __align__(16) float Wlds[2][128][137];    // 140,288 B
    __shared__ __align__(16) int   toklds[SEQLEN];       // 8 KB (prologue only)
    __shared__ float wacc_s[2][64];
    __shared__ float r_s[64];
    __shared__ float t1_s[64];

    const float* Gg = ws + 8192 + w * 4096;
    const int*   sq = seq + b * SEQLEN;

    // ---- stage token sequence ----
    {
        const int4* sq4 = (const int4*)sq;
        int4* tl4 = (int4*)toklds;
        #pragma unroll
        for (int i = 0; i < 4; ++i) tl4[tid + i * 128] = sq4[tid + i * 128];
    }
    __syncthreads();

    // ---- per-lane row-load offsets (into a 137-float chunk record) ----
    // layout: [0..35] W2 packed rows (row i at 8i - i(i-1)/2, len 8-i)
    //         [36..71] W1 packed rows (same shape)
    //         [72..135] -M2 dense (row i at 72+8i), [136] = 0.0 pad
    int offR[16];
    {
        const bool early = (l15 < 8);
        const int  ie    = early ? l15 : (l15 - 8);
        const int  rst   = 8 * ie - (ie * (ie - 1)) / 2;
        #pragma unroll
        for (int m = 0; m < 8; ++m)
            offR[m] = (early && m >= ie) ? (rst + m - ie) : 136;
        #pragma unroll
        for (int n = 0; n < 8; ++n)
            offR[8 + n] = early ? (72 + 8 * ie + n)
                                : ((n >= ie) ? (36 + rst + n - ie) : 136);
    }

    // ---- prologue: build per-chunk-16 tables (2 chunks per lane) ----
    {
        const float invL = 1.0f / (float)SEQLEN;
        #pragma unroll
        for (int qq = 0; qq < 2; ++qq) {
            const int C = lane + (qq << 6);          // 0..127
            int tE[8], tL[8];
            #pragma unroll
            for (int m = 0; m < 8; ++m) tE[m] = toklds[C * 16 + m];
            #pragma unroll
            for (int q = 0; q < 8; ++q) tL[q] = toklds[C * 16 + 8 + q];
            float Wp2[36], Wp1[36];
            build_wpack(tE, (float)(16 * C + 1) * invL, invL, is_e, false,    Wp2, Gg);
            build_wpack(tL, (float)(16 * C + 9) * invL, invL, is_e, C == 127, Wp1, Gg);

            float* WL = &Wlds[w][C][0];
            int ptr = 0;
            #pragma unroll
            for (int i = 0; i < 8; ++i)
                #pragma unroll
                for (int m = 0; m < 8; ++m)
                    if (m >= i) WL[ptr++] = Wp2[OM(m) + i];
            #pragma unroll
            for (int q = 0; q < 8; ++q)
                #pragma unroll
                for (int n = 0; n < 8; ++n)
                    if (n >= q) WL[ptr++] = Wp1[OM(n) + q];

            // Gx[q][m] = G[tokL_q][tokE_m]
            float Gx[64];
            #pragma unroll
            for (int q = 0; q < 8; ++q)
                #pragma unroll
                for (int m = 0; m < 8; ++m)
                    Gx[q * 8 + m] = Gg[tL[q] * 64 + tE[m]];

            // -M2[i][n] = - sum_q (sum_{m>=i} W2[i][m] Gx[q][m]) * W1[q][n]
            #pragma unroll
            for (int i = 0; i < 8; ++i) {
                float p[8];
                #pragma unroll
                for (int q = 0; q < 8; ++q) {
                    float acc = 0.0f;
                    #pragma unroll
                    for (int m = 0; m < 8; ++m)
                        if (m >= i) acc = fmaf(Wp2[OM(m) + i], Gx[q * 8 + m], acc);
                    p[q] = acc;
                }
                #pragma unroll
                for (int n = 0; n < 8; ++n) {
                    float acc = 0.0f;
                    #pragma unroll
                    for (int q = 0; q < 8; ++q)
                        if (q <= n) acc = fmaf(p[q], Wp1[OM(n) + q], acc);
                    WL[72 + 8 * i + n] = -acc;
                }
            }
            WL[136] = 0.0f;      // zero pad for invalid row slots
        }
    }
    __syncthreads();

    // ---- serial backward sweep: 128 chunk-16 bodies ----
    C16 A, B;
    float u, wc0 = 0.f, wc1 = 0.f, wc2 = 0.f, wc3 = 0.f;
    float sp[16];
    int tv2;

    A.tokv = sq[127 * 16 + l15];
    B.tokv = sq[126 * 16 + l15];
    tv2    = sq[125 * 16 + l15];
    #pragma unroll
    for (int j = 0; j < 16; ++j) A.tk[j] = RLI(A.tokv, j);
    #pragma unroll
    for (int j = 0; j < 16; ++j) A.grow[j] = Gg[A.tk[j] * 64 + lane];
    {
        const float* WL = &Wlds[w][127][0];
        #pragma unroll
        for (int m = 0; m < 16; ++m) A.row[m] = WL[offR[m]];
    }
    u = Gg[A.tk[15] * 64 + lane];          // query token = position 2047
    A.braw = __shfl(u, A.tokv, 64);        // exact (no later chunk)
    B.braw = __shfl(u, B.tokv, 64);        // missing chunk 127 -> B.bpp corr
    #pragma unroll
    for (int j = 0; j < 16; ++j) A.bpp[j] = 0.0f;
    #pragma unroll
    for (int j = 0; j < 16; ++j) sp[j] = 0.0f;

    auto body16 = [&](C16& cur, C16& nxt, int C) {
        const int cm1 = (C > 0) ? C - 1 : 0;
        const int cm3 = (C > 2) ? C - 3 : 0;

        // ---- spine head: corrected gather over prev chunk-16 ----
        float q0 = fmaf(cur.bpp[1],  sp[1],  cur.bpp[0]  * sp[0]);
        float q1 = fmaf(cur.bpp[3],  sp[3],  cur.bpp[2]  * sp[2]);
        float q2 = fmaf(cur.bpp[5],  sp[5],  cur.bpp[4]  * sp[4]);
        float q3 = fmaf(cur.bpp[7],  sp[7],  cur.bpp[6]  * sp[6]);
        float q4 = fmaf(cur.bpp[9],  sp[9],  cur.bpp[8]  * sp[8]);
        float q5 = fmaf(cur.bpp[11], sp[11], cur.bpp[10] * sp[10]);
        float q6 = fmaf(cur.bpp[13], sp[13], cur.bpp[12] * sp[12]);
        float q7 = fmaf(cur.bpp[15], sp[15], cur.bpp[14] * sp[14]);
        float tl = cur.braw - (((q0 + q1) + (q2 + q3)) + ((q4 + q5) + (q6 + q7)));

        // ---- t broadcast (round 1): 16-periodic value ----
        float t0 = SWZF(tl, 0),  t1 = SWZF(tl, 1),  t2 = SWZF(tl, 2),  t3 = SWZF(tl, 3);
        float t4 = SWZF(tl, 4),  t5 = SWZF(tl, 5),  t6 = SWZF(tl, 6),  t7 = SWZF(tl, 7);
        float t8 = SWZF(tl, 8),  t9 = SWZF(tl, 9),  tA = SWZF(tl, 10), tB = SWZF(tl, 11);
        float tC = SWZF(tl, 12), tD = SWZF(tl, 13), tE = SWZF(tl, 14), tF = SWZF(tl, 15);

        // ---- prefetch chunk C-1 (fills t latency; all off-spine) ----
        #pragma unroll
        for (int j = 0; j < 16; ++j) nxt.bpp[j] = __shfl(cur.grow[j], nxt.tokv, 64);
        #pragma unroll
        for (int j = 0; j < 16; ++j) nxt.tk[j] = RLI(nxt.tokv, j);
        #pragma unroll
        for (int j = 0; j < 16; ++j) nxt.grow[j] = Gg[nxt.tk[j] * 64 + lane];
        int tv3 = sq[cm3 * 16 + l15];

        // ---- distributed solve row (one round for BOTH sub-chunks) ----
        const float* R = cur.row;
        float a0 = fmaf(R[1],  t1, R[0]  * t0);
        float a1 = fmaf(R[3],  t3, R[2]  * t2);
        float a2 = fmaf(R[5],  t5, R[4]  * t4);
        float a3 = fmaf(R[7],  t7, R[6]  * t6);
        float a4 = fmaf(R[9],  t9, R[8]  * t8);
        float a5 = fmaf(R[11], tB, R[10] * tA);
        float a6 = fmaf(R[13], tD, R[12] * tC);
        float a7 = fmaf(R[15], tF, R[14] * tE);
        float sd = (((a0 + a1) + (a2 + a3)) + ((a4 + a5) + (a6 + a7)));

        // ---- s broadcast (round 2) ----
        float s0 = SWZF(sd, 0),  s1 = SWZF(sd, 1),  s2 = SWZF(sd, 2),  s3 = SWZF(sd, 3);
        float s4 = SWZF(sd, 4),  s5 = SWZF(sd, 5),  s6 = SWZF(sd, 6),  s7 = SWZF(sd, 7);
        float s8 = SWZF(sd, 8),  s9 = SWZF(sd, 9),  sA = SWZF(sd, 10), sB = SWZF(sd, 11);
        float sC = SWZF(sd, 12), sD = SWZF(sd, 13), sE = SWZF(sd, 14), sF = SWZF(sd, 15);

        // ---- row prefetch for C-1 (after s issue: keeps s queue shallow) ----
        {
            const float* WLn = &Wlds[w][cm1][0];
            #pragma unroll
            for (int m = 0; m < 16; ++m) nxt.row[m] = WLn[offR[m]];
        }

        // ---- u update, then braw for chunk C-2 (2-body slack) ----
        float dA = fmaf(cur.grow[0],  s0, fmaf(cur.grow[1],  s1, fmaf(cur.grow[2],  s2, cur.grow[3]  * s3)));
        float dB = fmaf(cur.grow[4],  s4, fmaf(cur.grow[5],  s5, fmaf(cur.grow[6],  s6, cur.grow[7]  * s7)));
        float dC = fmaf(cur.grow[8],  s8, fmaf(cur.grow[9],  s9, fmaf(cur.grow[10], sA, cur.grow[11] * sB)));
        float dD = fmaf(cur.grow[12], sC, fmaf(cur.grow[13], sD, fmaf(cur.grow[14], sE, cur.grow[15] * sF)));
        u -= (dA + dB) + (dC + dD);
        cur.braw = __shfl(u, tv2, 64);

        // ---- wacc[tok] += s (lane = token; 4 partials) ----
        wc0 += (lane == cur.tk[0])  ? s0 : 0.0f;
        wc1 += (lane == cur.tk[1])  ? s1 : 0.0f;
        wc2 += (lane == cur.tk[2])  ? s2 : 0.0f;
        wc3 += (lane == cur.tk[3])  ? s3 : 0.0f;
        wc0 += (lane == cur.tk[4])  ? s4 : 0.0f;
        wc1 += (lane == cur.tk[5])  ? s5 : 0.0f;
        wc2 += (lane == cur.tk[6])  ? s6 : 0.0f;
        wc3 += (lane == cur.tk[7])  ? s7 : 0.0f;
        wc0 += (lane == cur.tk[8])  ? s8 : 0.0f;
        wc1 += (lane == cur.tk[9])  ? s9 : 0.0f;
        wc2 += (lane == cur.tk[10]) ? sA : 0.0f;
        wc3 += (lane == cur.tk[11]) ? sB : 0.0f;
        wc0 += (lane == cur.tk[12]) ? sC : 0.0f;
        wc1 += (lane == cur.tk[13]) ? sD : 0.0f;
        wc2 += (lane == cur.tk[14]) ? sE : 0.0f;
        wc3 += (lane == cur.tk[15]) ? sF : 0.0f;

        // ---- rotate ----
        cur.tokv = tv2; tv2 = tv3;
        sp[0] = s0; sp[1] = s1; sp[2]  = s2; sp[3]  = s3;
        sp[4] = s4; sp[5] = s5; sp[6]  = s6; sp[7]  = s7;
        sp[8] = s8; sp[9] = s9; sp[10] = sA; sp[11] = sB;
        sp[12] = sC; sp[13] = sD; sp[14] = sE; sp[15] = sF;
    };

    for (int C = 127; C >= 1; C -= 2) {
        body16(A, B, C);
        body16(B, A, C - 1);
    }

    wacc_s[w][lane] = (wc0 + wc1) + (wc2 + wc3);
    __syncthreads();

    // r[w2][rho] = sum_tok wacc[w2][tok] * v[w2][tok][rho]
    if (tid < 64) {
        const int w2  = tid >> 5;
        const int rho = tid & 31;
        const float* vv = ws + 4096 + w2 * 2048;
        const float* wa = &wacc_s[w2][0];
        float acc = 0.0f;
        #pragma unroll 8
        for (int tok = 0; tok < 64; ++tok) acc = fmaf(wa[tok], vv[tok * 32 + rho], acc);
        r_s[tid] = acc;
    }
    __syncthreads();

    // out = (r @ Wrp.T + brp) @ Wo.T + bo
    if (tid < 64) {
        float acc = brp[tid];
        #pragma unroll 8
        for (int m = 0; m < 64; ++m) acc = fmaf(Wrp[tid * 64 + m], r_s[m], acc);
        t1_s[tid] = acc;
    }
    __syncthreads();
    if (tid < 64) {
        float acc = bo[tid];
        #pragma unroll 8
        for (int m = 0; m < 64; ++m) acc = fmaf(Wo[tid * 64 + m], t1_s[m], acc);
        out[b * 64 + tid] = acc;
    }
}

extern "C" void kernel_launch(void* const* d_in, const int* in_sizes, int n_in,
                              void* d_out, int out_size, void* d_ws, size_t ws_size,
                              hipStream_t stream)
{
    const int*   seq   = (const int*)  d_in[0];
    const float* embed = (const float*)d_in[1];
    const float* W1    = (const float*)d_in[2];
    const float* b1    = (const float*)d_in[3];
    const float* W2    = (const float*)d_in[4];
    const float* b2    = (const float*)d_in[5];
    const float* ln_g  = (const float*)d_in[6];
    const float* ln_b  = (const float*)d_in[7];
    const float* Ws    = (const float*)d_in[8];
    const float* bs    = (const float*)d_in[9];
    const float* We    = (const float*)d_in[10];
    const float* be    = (const float*)d_in[11];
    const float* Wrp   = (const float*)d_in[12];
    const float* brp   = (const float*)d_in[13];
    const float* Wo    = (const float*)d_in[14];
    const float* bo    = (const float*)d_in[15];
    float* ws  = (float*)d_ws;
    float* out = (float*)d_out;

    hipLaunchKernelGGL(vocab_kernel, dim3(VOCAB), dim3(256), 0, stream,
                       embed, W1, b1, W2, b2, ln_g, ln_b, Ws, bs, We, be, ws);
    hipLaunchKernelGGL(gram_kernel, dim3(8), dim3(256), 0, stream, ws);
    hipLaunchKernelGGL(scan_kernel, dim3(BATCH), dim3(128), 0, stream,
                       seq, ws, Wrp, brp, Wo, bo, out);
}